// Round 5
// baseline (290.812 us; speedup 1.0000x reference)
//
#include <hip/hip_runtime.h>

// QuantileLoss: scalar = ( sum_rows[ (p0-t0)^2+(p1-t1)^2+(p2-t2)^2 + 2*lower ] ) / (5N)
// lower = p3>p2 ? 1000 : (p3 > 0.95*t2 ? 0 : (p3-0.95*t2)^2)
//
// Ladder:
// R1 row loads cached:      101 us, eff read 2.66 TB/s (50% L3)
// R2 LDS staged cached:     105 us
// R3 NT 160B chunks:        150 us (1.46x NT over-fetch)
// R4 NT lane-contig + pipe:  95 us, eff 2.82 TB/s, 100% HBM
// R5 cached LDS, no atomic:  99.8 us, FETCH 134 MB (50% L3)
// R6 reg-only no barrier:    99.8 us, occ 65% -> not occupancy/burstiness
// R7 persistent dbuf:       105 us -> not pipelining
// R8 hybrid (preds NT, target cached): partial ~87-91 us (out of top-5),
//    harness 282.2. Matches SERIAL-COMPONENT model: t = HBM_bytes/2.8 +
//    L3_bytes/3.5 (MSHR x latency limiter; L3's shorter latency = more BW
//    from the same outstanding-miss budget). Parallel-paths ruled out.
// R9 (this): maximize L3-pinned bytes. Cache target (100.7 MB) + preds chunks
// 0..6143 (125.8 MB) = 226.5 MB resident (88% of L3); NT only the last
// 41.9 MB preds slice. Serial model predicts ~80 us partial.
// Discriminates fill-eviction: if FETCH stays ~130 MB and time flat, the
// poison fill forces ~50% residency and R8 was already the floor.

#define NROWS 8388608                      // 2^23
#define ROWS_PER_CHUNK 1024
#define NCHUNKS (NROWS / ROWS_PER_CHUNK)   // 8192
#define PCHUNK (ROWS_PER_CHUNK * 5)        // 5120 floats = 20 KB
#define TCHUNK (ROWS_PER_CHUNK * 3)        // 3072 floats = 12 KB
#define GRID 2048
#define CHUNKS_PER_BLOCK (NCHUNKS / GRID)  // 4
#define CACHED_ITERS 3                     // preds iters 0-2 cached (125.8 MB), iter 3 NT

typedef float v4f __attribute__((ext_vector_type(4)));

__global__ void __launch_bounds__(256) qloss_partial(
    const float* __restrict__ preds,
    const float* __restrict__ target,
    double* __restrict__ ws)
{
    __shared__ float sp[PCHUNK];
    __shared__ float st[TCHUNK];

    const int t = threadIdx.x;
    double acc = 0.0;

    // Prologue: chunk 0 (iter 0 -> preds cached), target always cached.
    v4f rp[5], rt[3];
    {
        const v4f* gp = (const v4f*)(preds + (size_t)blockIdx.x * PCHUNK);
        const v4f* gt = (const v4f*)(target + (size_t)blockIdx.x * TCHUNK);
        #pragma unroll
        for (int k = 0; k < 5; ++k) rp[k] = gp[t + k * 256];
        #pragma unroll
        for (int k = 0; k < 3; ++k) rt[k] = gt[t + k * 256];
    }

    #pragma unroll
    for (int i = 0; i < CHUNKS_PER_BLOCK; ++i) {
        // Stage current chunk into LDS (lane-contiguous, coalesced).
        #pragma unroll
        for (int k = 0; k < 5; ++k) ((v4f*)sp)[t + k * 256] = rp[k];
        #pragma unroll
        for (int k = 0; k < 3; ++k) ((v4f*)st)[t + k * 256] = rt[k];
        __syncthreads();

        // Next chunk's loads stay in flight during compute (2-stage pipeline).
        // i is compile-time (full unroll): iters 1..CACHED_ITERS-1 cached,
        // final iter NT (the 41.9 MB of preds that can't fit L3).
        if (i + 1 < CHUNKS_PER_BLOCK) {
            const int nc = blockIdx.x + (i + 1) * GRID;
            const v4f* gp = (const v4f*)(preds + (size_t)nc * PCHUNK);
            const v4f* gt = (const v4f*)(target + (size_t)nc * TCHUNK);
            if (i + 1 < CACHED_ITERS) {
                #pragma unroll
                for (int k = 0; k < 5; ++k) rp[k] = gp[t + k * 256];
            } else {
                #pragma unroll
                for (int k = 0; k < 5; ++k) rp[k] = __builtin_nontemporal_load(gp + t + k * 256);
            }
            #pragma unroll
            for (int k = 0; k < 3; ++k) rt[k] = gt[t + k * 256];
        }

        // Compute 4 rows/thread out of LDS (stride 5/3: 2-way bank alias, free).
        float sum = 0.0f;
        #pragma unroll
        for (int rr = 0; rr < 4; ++rr) {
            const int r = t + rr * 256;
            const float p0 = sp[5*r + 0];
            const float p1 = sp[5*r + 1];
            const float p2 = sp[5*r + 2];
            const float p3 = sp[5*r + 3];
            const float t0 = st[3*r + 0];
            const float t1 = st[3*r + 1];
            const float t2 = st[3*r + 2];

            const float a0 = p0 - t0;
            const float a1 = p1 - t1;
            const float a2 = p2 - t2;
            const float m  = a0*a0 + a1*a1 + a2*a2;

            const float q = t2 * 0.95f;
            const float d = p3 - q;
            const float lower = (p3 > p2) ? 1000.0f : ((p3 > q) ? 0.0f : d * d);

            sum += m + 2.0f * lower;
        }
        acc += (double)sum;
        __syncthreads();   // LDS safe to overwrite next iteration
    }

    // wave64 shuffle reduce -> per-block partial. No atomics, no memset needed.
    #pragma unroll
    for (int off = 32; off > 0; off >>= 1)
        acc += __shfl_down(acc, off, 64);

    __shared__ double red[4];
    const int lane = t & 63;
    const int wave = t >> 6;
    if (lane == 0) red[wave] = acc;
    __syncthreads();

    if (t == 0)
        ws[blockIdx.x] = red[0] + red[1] + red[2] + red[3];
}

__global__ void __launch_bounds__(256) qloss_final(
    const double* __restrict__ ws, float* __restrict__ out)
{
    const int t = threadIdx.x;
    double acc = 0.0;
    #pragma unroll
    for (int i = 0; i < GRID / 256; ++i)    // 8 partials/thread, 16 KB total
        acc += ws[t + i * 256];

    #pragma unroll
    for (int off = 32; off > 0; off >>= 1)
        acc += __shfl_down(acc, off, 64);

    __shared__ double red[4];
    const int lane = t & 63;
    const int wave = t >> 6;
    if (lane == 0) red[wave] = acc;
    __syncthreads();

    if (t == 0)
        *out = (float)((red[0] + red[1] + red[2] + red[3]) / (5.0 * (double)NROWS));
}

extern "C" void kernel_launch(void* const* d_in, const int* in_sizes, int n_in,
                              void* d_out, int out_size, void* d_ws, size_t ws_size,
                              hipStream_t stream)
{
    const float* preds  = (const float*)d_in[0];
    const float* target = (const float*)d_in[1];
    float* out  = (float*)d_out;
    double* ws  = (double*)d_ws;

    // Every ws slot [0, GRID) is overwritten by qloss_partial before qloss_final
    // reads it -> no memset needed despite workspace poisoning.
    qloss_partial<<<GRID, 256, 0, stream>>>(preds, target, ws);
    qloss_final<<<1, 256, 0, stream>>>(ws, out);
}

// Round 6
// 280.196 us; speedup vs baseline: 1.0379x; 1.0379x over previous
//
#include <hip/hip_runtime.h>

// QuantileLoss: scalar = ( sum_rows[ (p0-t0)^2+(p1-t1)^2+(p2-t2)^2 + 2*lower ] ) / (5N)
// lower = p3>p2 ? 1000 : (p3 > 0.95*t2 ? 0 : (p3-0.95*t2)^2)
//
// Ladder:
// R1 row loads cached:      101 us, eff read 2.66 TB/s (50% L3)
// R2 LDS staged cached:     105 us
// R3 NT 160B chunks:        150 us (1.46x NT over-fetch)
// R4 NT lane-contig + pipe:  95 us, eff 2.82 TB/s, 100% HBM
// R5 cached LDS, no atomic:  99.8 us, FETCH 134 MB (50% L3)
// R6 reg-only no barrier:    99.8 us, occ 65% -> not occupancy/burstiness
// R7 persistent dbuf:       105 us -> not pipelining
// R8 preds NT + target cached: ~89 us partial, harness 282.2  <- BEST
// R9 + preds iters 0-2 cached: ~97 us, harness 290.8 -> L3 THRASH.
//
// Mechanism (fits all 9 points): read-return is latency x outstanding bound:
// ~2.8 TB/s HBM-served, ~3.4 TB/s L3-served (vs writes 6.9 TB/s, m13 copy
// read-half 3.15). Poison fill streams (no allocate); cross-iteration L3
// residency = what the kernel allocates, surviving ~e^(-A/256MB). R8's
// A=100MB (target only) -> survival .68, t = 168/2.82 + .68*100/3.4 +
// .32*100/2.9 ~= 90 us = measured. R9's A=226 -> survival .41 -> 96 us =
// measured. Optimum over A is ~88.5-89.5 us at A~100-140 => R8 is within
// ~1 us of model-optimal. This round: restore R8 verbatim (reproduction
// run; R9 was a regression). Expect harness 280-285.

#define NROWS 8388608                      // 2^23
#define ROWS_PER_CHUNK 1024
#define NCHUNKS (NROWS / ROWS_PER_CHUNK)   // 8192
#define PCHUNK (ROWS_PER_CHUNK * 5)        // 5120 floats = 20 KB
#define TCHUNK (ROWS_PER_CHUNK * 3)        // 3072 floats = 12 KB
#define GRID 2048
#define CHUNKS_PER_BLOCK (NCHUNKS / GRID)  // 4

typedef float v4f __attribute__((ext_vector_type(4)));

__global__ void __launch_bounds__(256) qloss_partial(
    const float* __restrict__ preds,
    const float* __restrict__ target,
    double* __restrict__ ws)
{
    __shared__ float sp[PCHUNK];
    __shared__ float st[TCHUNK];

    const int t = threadIdx.x;
    double acc = 0.0;

    // Prologue: chunk 0. preds NT (HBM path, no L3 allocation),
    // target cached (100.7 MB allocation -> stays mostly L3-resident).
    v4f rp[5], rt[3];
    {
        const v4f* gp = (const v4f*)(preds + (size_t)blockIdx.x * PCHUNK);
        const v4f* gt = (const v4f*)(target + (size_t)blockIdx.x * TCHUNK);
        #pragma unroll
        for (int k = 0; k < 5; ++k) rp[k] = __builtin_nontemporal_load(gp + t + k * 256);
        #pragma unroll
        for (int k = 0; k < 3; ++k) rt[k] = gt[t + k * 256];
    }

    #pragma unroll
    for (int i = 0; i < CHUNKS_PER_BLOCK; ++i) {
        // Stage current chunk into LDS (lane-contiguous, coalesced).
        #pragma unroll
        for (int k = 0; k < 5; ++k) ((v4f*)sp)[t + k * 256] = rp[k];
        #pragma unroll
        for (int k = 0; k < 3; ++k) ((v4f*)st)[t + k * 256] = rt[k];
        __syncthreads();

        // Next chunk's loads stay in flight during compute (2-stage pipeline).
        if (i + 1 < CHUNKS_PER_BLOCK) {
            const int nc = blockIdx.x + (i + 1) * GRID;
            const v4f* gp = (const v4f*)(preds + (size_t)nc * PCHUNK);
            const v4f* gt = (const v4f*)(target + (size_t)nc * TCHUNK);
            #pragma unroll
            for (int k = 0; k < 5; ++k) rp[k] = __builtin_nontemporal_load(gp + t + k * 256);
            #pragma unroll
            for (int k = 0; k < 3; ++k) rt[k] = gt[t + k * 256];
        }

        // Compute 4 rows/thread out of LDS (stride 5/3: 2-way bank alias, free).
        float sum = 0.0f;
        #pragma unroll
        for (int rr = 0; rr < 4; ++rr) {
            const int r = t + rr * 256;
            const float p0 = sp[5*r + 0];
            const float p1 = sp[5*r + 1];
            const float p2 = sp[5*r + 2];
            const float p3 = sp[5*r + 3];
            const float t0 = st[3*r + 0];
            const float t1 = st[3*r + 1];
            const float t2 = st[3*r + 2];

            const float a0 = p0 - t0;
            const float a1 = p1 - t1;
            const float a2 = p2 - t2;
            const float m  = a0*a0 + a1*a1 + a2*a2;

            const float q = t2 * 0.95f;
            const float d = p3 - q;
            const float lower = (p3 > p2) ? 1000.0f : ((p3 > q) ? 0.0f : d * d);

            sum += m + 2.0f * lower;
        }
        acc += (double)sum;
        __syncthreads();   // LDS safe to overwrite next iteration
    }

    // wave64 shuffle reduce -> per-block partial. No atomics, no memset needed.
    #pragma unroll
    for (int off = 32; off > 0; off >>= 1)
        acc += __shfl_down(acc, off, 64);

    __shared__ double red[4];
    const int lane = t & 63;
    const int wave = t >> 6;
    if (lane == 0) red[wave] = acc;
    __syncthreads();

    if (t == 0)
        ws[blockIdx.x] = red[0] + red[1] + red[2] + red[3];
}

__global__ void __launch_bounds__(256) qloss_final(
    const double* __restrict__ ws, float* __restrict__ out)
{
    const int t = threadIdx.x;
    double acc = 0.0;
    #pragma unroll
    for (int i = 0; i < GRID / 256; ++i)    // 8 partials/thread, 16 KB total
        acc += ws[t + i * 256];

    #pragma unroll
    for (int off = 32; off > 0; off >>= 1)
        acc += __shfl_down(acc, off, 64);

    __shared__ double red[4];
    const int lane = t & 63;
    const int wave = t >> 6;
    if (lane == 0) red[wave] = acc;
    __syncthreads();

    if (t == 0)
        *out = (float)((red[0] + red[1] + red[2] + red[3]) / (5.0 * (double)NROWS));
}

extern "C" void kernel_launch(void* const* d_in, const int* in_sizes, int n_in,
                              void* d_out, int out_size, void* d_ws, size_t ws_size,
                              hipStream_t stream)
{
    const float* preds  = (const float*)d_in[0];
    const float* target = (const float*)d_in[1];
    float* out  = (float*)d_out;
    double* ws  = (double*)d_ws;

    // Every ws slot [0, GRID) is overwritten by qloss_partial before qloss_final
    // reads it -> no memset needed despite workspace poisoning.
    qloss_partial<<<GRID, 256, 0, stream>>>(preds, target, ws);
    qloss_final<<<1, 256, 0, stream>>>(ws, out);
}